// Round 2
// baseline (1738.950 us; speedup 1.0000x reference)
//
#include <hip/hip_runtime.h>
#include <hip/hip_bf16.h>

typedef short bf16x8 __attribute__((ext_vector_type(8)));
typedef float f32x4 __attribute__((ext_vector_type(4)));
typedef unsigned short u16;
typedef unsigned int u32;
typedef unsigned long long u64;

#define AS1 __attribute__((address_space(1)))
#define AS3 __attribute__((address_space(3)))

__device__ __forceinline__ u16 f2bf(float f) {
    __hip_bfloat16 h = __float2bfloat16(f);
    u16 r;
    __builtin_memcpy(&r, &h, 2);
    return r;
}
__device__ __forceinline__ float bf2f(u16 u) {
    u32 v = ((u32)u) << 16;
    float f;
    __builtin_memcpy(&f, &v, 4);
    return f;
}

// T=128 B=256 OBS=512 ENC=256 H=512 A=18 N=32768

// ---------------- prep: weight fp32 -> bf16 conversions (x handled in gemm1) ----------------
constexpr int NW1  = 256 * 512;
constexpr int NW2  = 256 * 256;
constexpr int NWIH = 1536 * 256;

__global__ __launch_bounds__(256) void prep_kernel(
    const float* __restrict__ w1, const float* __restrict__ w2,
    const float* __restrict__ wih, const float* __restrict__ wact,
    const float* __restrict__ wcrit,
    u16* __restrict__ w1b, u16* __restrict__ w2b,
    u16* __restrict__ wihb, u16* __restrict__ wcatb) {
    long long gid = (long long)blockIdx.x * 256 + threadIdx.x;
    long long i4 = gid * 4;
    const float* src;
    u16* dst;
    if (i4 < NW1) { src = w1; dst = w1b; }
    else if ((i4 -= NW1) < NW2) { src = w2; dst = w2b; }
    else if ((i4 -= NW2) < NWIH) { src = wih; dst = wihb; }
    else {
        i4 -= NWIH;  // wcat region, 32x512 padded actor(18)+critic(1)+zeros
        #pragma unroll
        for (int e = 0; e < 4; e++) {
            long long idx = i4 + e;
            int row = (int)(idx >> 9), col = (int)(idx & 511);
            float v = (row < 18) ? wact[row * 512 + col]
                    : (row == 18 ? wcrit[col] : 0.f);
            wcatb[idx] = f2bf(v);
        }
        return;
    }
    float4 v = *reinterpret_cast<const float4*>(src + i4);
    uint2 p;
    p.x = (u32)f2bf(v.x) | ((u32)f2bf(v.y) << 16);
    p.y = (u32)f2bf(v.z) | ((u32)f2bf(v.w) << 16);
    *reinterpret_cast<uint2*>(dst + i4) = p;
}

// ---------------- GEMM1: C = relu(A_fp32 @ B^T + bias) -> bf16 ----------------
// A: MxK fp32 row-major (converted to bf16 during LDS staging). B: NxK bf16.
__global__ __launch_bounds__(256) void gemm_a32_bt_kernel(
    const float* __restrict__ A, const u16* __restrict__ B,
    const float* __restrict__ bias, u16* __restrict__ out,
    int M, int N, int K) {
    __shared__ u16 As[128 * 64];
    __shared__ u16 Bs[128 * 64];
    int tid = threadIdx.x;
    int lane = tid & 63, wave = tid >> 6;
    int m16 = lane & 15, quad = lane >> 4;
    int nb = N >> 7;
    int bm = blockIdx.x / nb, bn = blockIdx.x % nb;
    int wm = wave >> 1, wn = wave & 1;

    f32x4 acc[4][4];
    #pragma unroll
    for (int i = 0; i < 4; i++)
        #pragma unroll
        for (int j = 0; j < 4; j++) acc[i][j] = (f32x4){0.f, 0.f, 0.f, 0.f};

    const int rbase = wave * 32 + (lane >> 3);
    const int cpr = lane & 7;
    const int ar = tid >> 1, ah = (tid & 1) * 32;  // A-staging: 2 threads/row
    int kiters = K >> 6;
    for (int kb = 0; kb < kiters; kb++) {
        #pragma unroll
        for (int i = 0; i < 4; i++) {
            int r = rbase + i * 8;
            int cg = cpr ^ (r & 7);
            const u16* gb_ = B + (long long)(bn * 128 + r) * K + kb * 64 + cg * 8;
            __builtin_amdgcn_global_load_lds((const AS1 u32*)gb_, (AS3 u32*)&Bs[r * 64 + cpr * 8], 16, 0, 0);
        }
        const float* ga = A + (long long)(bm * 128 + ar) * K + kb * 64 + ah;
        #pragma unroll
        for (int g = 0; g < 4; g++) {
            float4 v0 = *reinterpret_cast<const float4*>(ga + g * 8);
            float4 v1 = *reinterpret_cast<const float4*>(ga + g * 8 + 4);
            uint4 pk;
            pk.x = (u32)f2bf(v0.x) | ((u32)f2bf(v0.y) << 16);
            pk.y = (u32)f2bf(v0.z) | ((u32)f2bf(v0.w) << 16);
            pk.z = (u32)f2bf(v1.x) | ((u32)f2bf(v1.y) << 16);
            pk.w = (u32)f2bf(v1.z) | ((u32)f2bf(v1.w) << 16);
            int sc = ((ah >> 3) + g) ^ (ar & 7);  // XOR swizzle
            *reinterpret_cast<uint4*>(&As[ar * 64 + sc * 8]) = pk;
        }
        __syncthreads();
        #pragma unroll
        for (int ks = 0; ks < 2; ks++) {
            bf16x8 af[4], bfr[4];
            int lc = ks * 4 + quad;
            #pragma unroll
            for (int mt = 0; mt < 4; mt++) {
                int m = wm * 64 + mt * 16 + m16;
                af[mt] = *reinterpret_cast<const bf16x8*>(&As[m * 64 + (lc ^ (m & 7)) * 8]);
            }
            #pragma unroll
            for (int nt = 0; nt < 4; nt++) {
                int n = wn * 64 + nt * 16 + m16;
                bfr[nt] = *reinterpret_cast<const bf16x8*>(&Bs[n * 64 + (lc ^ (n & 7)) * 8]);
            }
            #pragma unroll
            for (int mt = 0; mt < 4; mt++)
                #pragma unroll
                for (int nt = 0; nt < 4; nt++)
                    acc[mt][nt] = __builtin_amdgcn_mfma_f32_16x16x32_bf16(af[mt], bfr[nt], acc[mt][nt], 0, 0, 0);
        }
        __syncthreads();
    }
    #pragma unroll
    for (int nt = 0; nt < 4; nt++) {
        int n = bn * 128 + wn * 64 + nt * 16 + m16;
        float bv = bias[n];
        #pragma unroll
        for (int mt = 0; mt < 4; mt++) {
            #pragma unroll
            for (int i = 0; i < 4; i++) {
                int m = bm * 128 + wm * 64 + mt * 16 + quad * 4 + i;
                float v = acc[mt][nt][i] + bv;
                out[(long long)m * N + n] = f2bf(fmaxf(v, 0.f));
            }
        }
    }
}

// ---------------- tiled GEMM: bf16 A/B. mode 0: relu->bf16 rowmajor. mode 1: gx scatter bf16 ----------------
__global__ __launch_bounds__(256) void gemm_bt_kernel(
    const u16* __restrict__ A, const u16* __restrict__ B,
    const float* __restrict__ bias, u16* __restrict__ out,
    int M, int N, int K, int mode) {
    __shared__ u16 As[128 * 64];
    __shared__ u16 Bs[128 * 64];
    int tid = threadIdx.x;
    int lane = tid & 63, wave = tid >> 6;
    int m16 = lane & 15, quad = lane >> 4;
    int nb = N >> 7;
    int bm = blockIdx.x / nb, bn = blockIdx.x % nb;
    int wm = wave >> 1, wn = wave & 1;

    f32x4 acc[4][4];
    #pragma unroll
    for (int i = 0; i < 4; i++)
        #pragma unroll
        for (int j = 0; j < 4; j++) acc[i][j] = (f32x4){0.f, 0.f, 0.f, 0.f};

    const int rbase = wave * 32 + (lane >> 3);
    const int cpr = lane & 7;
    int kiters = K >> 6;
    for (int kb = 0; kb < kiters; kb++) {
        #pragma unroll
        for (int i = 0; i < 4; i++) {
            int r = rbase + i * 8;
            int cg = cpr ^ (r & 7);
            const u16* ga = A + (long long)(bm * 128 + r) * K + kb * 64 + cg * 8;
            const u16* gb_ = B + (long long)(bn * 128 + r) * K + kb * 64 + cg * 8;
            __builtin_amdgcn_global_load_lds((const AS1 u32*)ga, (AS3 u32*)&As[r * 64 + cpr * 8], 16, 0, 0);
            __builtin_amdgcn_global_load_lds((const AS1 u32*)gb_, (AS3 u32*)&Bs[r * 64 + cpr * 8], 16, 0, 0);
        }
        __syncthreads();
        #pragma unroll
        for (int ks = 0; ks < 2; ks++) {
            bf16x8 af[4], bfr[4];
            int lc = ks * 4 + quad;
            #pragma unroll
            for (int mt = 0; mt < 4; mt++) {
                int m = wm * 64 + mt * 16 + m16;
                af[mt] = *reinterpret_cast<const bf16x8*>(&As[m * 64 + (lc ^ (m & 7)) * 8]);
            }
            #pragma unroll
            for (int nt = 0; nt < 4; nt++) {
                int n = wn * 64 + nt * 16 + m16;
                bfr[nt] = *reinterpret_cast<const bf16x8*>(&Bs[n * 64 + (lc ^ (n & 7)) * 8]);
            }
            #pragma unroll
            for (int mt = 0; mt < 4; mt++)
                #pragma unroll
                for (int nt = 0; nt < 4; nt++)
                    acc[mt][nt] = __builtin_amdgcn_mfma_f32_16x16x32_bf16(af[mt], bfr[nt], acc[mt][nt], 0, 0, 0);
        }
        __syncthreads();
    }
    if (mode == 0) {
        #pragma unroll
        for (int nt = 0; nt < 4; nt++) {
            int n = bn * 128 + wn * 64 + nt * 16 + m16;
            float bv = bias[n];
            #pragma unroll
            for (int mt = 0; mt < 4; mt++) {
                #pragma unroll
                for (int i = 0; i < 4; i++) {
                    int m = bm * 128 + wm * 64 + mt * 16 + quad * 4 + i;
                    float v = acc[mt][nt][i] + bv;
                    out[(long long)m * N + n] = f2bf(fmaxf(v, 0.f));
                }
            }
        }
    } else {
        // gx scatter (bf16): [t][gb][gu][b_local(16)][gate_local(96)]
        #pragma unroll
        for (int nt = 0; nt < 4; nt++) {
            int n = bn * 128 + wn * 64 + nt * 16 + m16;
            float bv = bias[n];
            int gkind = n >> 9, gj = n & 511;
            int gu = gj >> 5;
            int gate_local = gkind * 32 + (gj & 31);
            #pragma unroll
            for (int mt = 0; mt < 4; mt++) {
                #pragma unroll
                for (int i = 0; i < 4; i++) {
                    int m = bm * 128 + wm * 64 + mt * 16 + quad * 4 + i;
                    int t = m >> 8, bg = m & 255;
                    long long dst = ((((long long)t * 16 + (bg >> 4)) * 16 + gu) * 16 + (bg & 15)) * 96 + gate_local;
                    out[dst] = f2bf(acc[mt][nt][i] + bv);
                }
            }
        }
    }
}

// ---------------- GRU scan (cooperative, 256 wgs = 16 batch-groups x 16 unit-groups) ----------------
__global__ __launch_bounds__(256) void scan_kernel(
    const float* __restrict__ gru_state, const float* __restrict__ done,
    const float* __restrict__ w_hh, const float* __restrict__ b_hh,
    const u16* __restrict__ gx, u16* h_pub, u16* hidden,
    float* h_last, int* flags) {
    __shared__ u16 h_lds[16 * 520];        // 16 batch rows x 512 (+8 pad)
    __shared__ float partial[4 * 16 * 96]; // per-wave K-split partials
    int tid = threadIdx.x;
    int lane = tid & 63, wave = tid >> 6;
    int m16 = lane & 15, quad = lane >> 4;
    int gb = blockIdx.x & 15, gu = blockIdx.x >> 4;

    // w_hh slice -> register-resident MFMA B-fragments (fp32->bf16, loaded once)
    bf16x8 wfrag[6][4];
    #pragma unroll
    for (int nt = 0; nt < 6; nt++) {
        int g = nt * 16 + m16;                       // local gate 0..95
        int row = (g >> 5) * 512 + gu * 32 + (g & 31);
        #pragma unroll
        for (int ks = 0; ks < 4; ks++) {
            int k0 = wave * 128 + ks * 32 + quad * 8;
            const float* wp = w_hh + row * 512 + k0;
            float4 v0 = *reinterpret_cast<const float4*>(wp);
            float4 v1 = *reinterpret_cast<const float4*>(wp + 4);
            bf16x8 f;
            f[0] = (short)f2bf(v0.x); f[1] = (short)f2bf(v0.y);
            f[2] = (short)f2bf(v0.z); f[3] = (short)f2bf(v0.w);
            f[4] = (short)f2bf(v1.x); f[5] = (short)f2bf(v1.y);
            f[6] = (short)f2bf(v1.z); f[7] = (short)f2bf(v1.w);
            wfrag[nt][ks] = f;
        }
    }
    int b_ = tid >> 4, jj = (tid & 15) * 2;   // owned element pair (b_, jj/jj+1)
    int bglob = gb * 16 + b_;
    int unit = gu * 32 + jj;
    float bhr0 = b_hh[unit],        bhr1 = b_hh[unit + 1];
    float bhz0 = b_hh[512 + unit],  bhz1 = b_hh[512 + unit + 1];
    float bhn0 = b_hh[1024 + unit], bhn1 = b_hh[1024 + unit + 1];
    float hs0 = gru_state[bglob * 512 + unit];
    float hs1 = gru_state[bglob * 512 + unit + 1];

    // publish h[0] into buffer 0
    {
        u32 p = (u32)f2bf(hs0) | ((u32)f2bf(hs1) << 16);
        u32* dst = (u32*)h_pub + (bglob * 512 + unit) / 2;
        __hip_atomic_store(dst, p, __ATOMIC_RELAXED, __HIP_MEMORY_SCOPE_AGENT);
    }
    __syncthreads();   // drains vmcnt before flag
    if (tid == 0)
        __hip_atomic_fetch_add(&flags[gb], 1, __ATOMIC_RELEASE, __HIP_MEMORY_SCOPE_AGENT);

    const int fillcol = (tid & 15) * 32;
    for (int t = 0; t < 128; t++) {
        // prefetch gx / done (independent of the flag)
        const u16* gxp = gx + ((size_t)((t * 16 + gb) * 16 + gu) * 16 + b_) * 96;
        u32 pr = *reinterpret_cast<const u32*>(gxp + jj);
        u32 pz = *reinterpret_cast<const u32*>(gxp + 32 + jj);
        u32 pn = *reinterpret_cast<const u32*>(gxp + 64 + jj);
        float grx = bf2f((u16)pr), gry = bf2f((u16)(pr >> 16));
        float gzx = bf2f((u16)pz), gzy = bf2f((u16)(pz >> 16));
        float gnx = bf2f((u16)pn), gny = bf2f((u16)(pn >> 16));
        float dne = done[t * 256 + bglob];

        if (tid == 0) {
            while (__hip_atomic_load(&flags[t * 16 + gb], __ATOMIC_ACQUIRE, __HIP_MEMORY_SCOPE_AGENT) < 16)
                __builtin_amdgcn_s_sleep(1);
        }
        __syncthreads();
        // fill h_lds row b_ cols [fillcol, fillcol+32) from h_pub[t&1], applying done reset
        {
            const u64* src = (const u64*)(h_pub + (size_t)(t & 1) * (256 * 512)) + (bglob * 512 + fillcol) / 4;
            bool keep = dne < 0.5f;   // done is exactly 0.0/1.0
            #pragma unroll
            for (int q = 0; q < 8; q++) {
                u64 v = __hip_atomic_load((u64*)(src + q), __ATOMIC_RELAXED, __HIP_MEMORY_SCOPE_AGENT);
                if (!keep) v = 0;
                *reinterpret_cast<u64*>(&h_lds[b_ * 520 + fillcol + q * 4]) = v;
            }
        }
        __syncthreads();
        // gh slice = h(16x512) @ w_hh_slice^T(96x512): K-split over 4 waves
        f32x4 acc[6];
        #pragma unroll
        for (int nt = 0; nt < 6; nt++) acc[nt] = (f32x4){0.f, 0.f, 0.f, 0.f};
        #pragma unroll
        for (int ks = 0; ks < 4; ks++) {
            bf16x8 a = *reinterpret_cast<const bf16x8*>(&h_lds[m16 * 520 + wave * 128 + ks * 32 + quad * 8]);
            #pragma unroll
            for (int nt = 0; nt < 6; nt++)
                acc[nt] = __builtin_amdgcn_mfma_f32_16x16x32_bf16(a, wfrag[nt][ks], acc[nt], 0, 0, 0);
        }
        #pragma unroll
        for (int nt = 0; nt < 6; nt++)
            #pragma unroll
            for (int i = 0; i < 4; i++)
                partial[wave * 1536 + (quad * 4 + i) * 96 + nt * 16 + m16] = acc[nt][i];
        __syncthreads();
        // reduce K-split partials + gates (each thread: 2 hidden units)
        float sr0 = 0, sr1 = 0, sz0 = 0, sz1 = 0, sn0 = 0, sn1 = 0;
        #pragma unroll
        for (int w = 0; w < 4; w++) {
            const float* p = &partial[w * 1536 + b_ * 96];
            float2 a0 = *reinterpret_cast<const float2*>(p + jj);
            float2 a1 = *reinterpret_cast<const float2*>(p + 32 + jj);
            float2 a2 = *reinterpret_cast<const float2*>(p + 64 + jj);
            sr0 += a0.x; sr1 += a0.y;
            sz0 += a1.x; sz1 += a1.y;
            sn0 += a2.x; sn1 += a2.y;
        }
        float scale = 1.f - dne;
        hs0 *= scale; hs1 *= scale;
        float r0 = 1.f / (1.f + __expf(-(grx + sr0 + bhr0)));
        float r1 = 1.f / (1.f + __expf(-(gry + sr1 + bhr1)));
        float z0 = 1.f / (1.f + __expf(-(gzx + sz0 + bhz0)));
        float z1 = 1.f / (1.f + __expf(-(gzy + sz1 + bhz1)));
        float pn0 = gnx + r0 * (sn0 + bhn0);
        float pn1 = gny + r1 * (sn1 + bhn1);
        float n0 = 1.f - 2.f / (__expf(2.f * pn0) + 1.f);   // tanh
        float n1 = 1.f - 2.f / (__expf(2.f * pn1) + 1.f);
        hs0 = (1.f - z0) * n0 + z0 * hs0;
        hs1 = (1.f - z1) * n1 + z1 * hs1;
        u32 packed = (u32)f2bf(hs0) | ((u32)f2bf(hs1) << 16);
        ((u32*)hidden)[((long long)(t * 256 + bglob) * 512 + unit) / 2] = packed;
        {
            u32* dst = (u32*)(h_pub + (size_t)((t + 1) & 1) * (256 * 512)) + (bglob * 512 + unit) / 2;
            __hip_atomic_store(dst, packed, __ATOMIC_RELAXED, __HIP_MEMORY_SCOPE_AGENT);
        }
        if (t == 127) {
            h_last[bglob * 512 + unit] = hs0;
            h_last[bglob * 512 + unit + 1] = hs1;
        }
        __syncthreads();   // drains vmcnt: all publish stores complete
        if (tid == 0)
            __hip_atomic_fetch_add(&flags[(t + 1) * 16 + gb], 1, __ATOMIC_RELEASE, __HIP_MEMORY_SCOPE_AGENT);
    }
}

// ---------------- heads: logits/log_softmax/entropy/value ----------------
__global__ __launch_bounds__(256) void heads_kernel(
    const u16* __restrict__ hidden, const u16* __restrict__ wcat,
    const float* __restrict__ b_actor, const float* __restrict__ b_critic,
    const int* __restrict__ action, float* __restrict__ out) {
    __shared__ float cls[4][16][34];
    int tid = threadIdx.x, lane = tid & 63, wave = tid >> 6;
    int m16 = lane & 15, quad = lane >> 4;
    int r0 = (blockIdx.x * 4 + wave) * 16;
    f32x4 acc0 = (f32x4){0.f, 0.f, 0.f, 0.f}, acc1 = (f32x4){0.f, 0.f, 0.f, 0.f};
    #pragma unroll
    for (int ks = 0; ks < 16; ks++) {
        bf16x8 a = *reinterpret_cast<const bf16x8*>(&hidden[(long long)(r0 + m16) * 512 + ks * 32 + quad * 8]);
        bf16x8 b0 = *reinterpret_cast<const bf16x8*>(&wcat[m16 * 512 + ks * 32 + quad * 8]);
        bf16x8 b1 = *reinterpret_cast<const bf16x8*>(&wcat[(16 + m16) * 512 + ks * 32 + quad * 8]);
        acc0 = __builtin_amdgcn_mfma_f32_16x16x32_bf16(a, b0, acc0, 0, 0, 0);
        acc1 = __builtin_amdgcn_mfma_f32_16x16x32_bf16(a, b1, acc1, 0, 0, 0);
    }
    #pragma unroll
    for (int i = 0; i < 4; i++) {
        cls[wave][quad * 4 + i][m16] = acc0[i];
        cls[wave][quad * 4 + i][16 + m16] = acc1[i];
    }
    __syncthreads();
    if (lane < 16) {
        int row = r0 + lane;
        float lg[18];
        float mx = -1e30f;
        #pragma unroll
        for (int a2 = 0; a2 < 18; a2++) {
            lg[a2] = cls[wave][lane][a2] + b_actor[a2];
            mx = fmaxf(mx, lg[a2]);
        }
        float s = 0.f, sl = 0.f;
        #pragma unroll
        for (int a2 = 0; a2 < 18; a2++) {
            float e = __expf(lg[a2] - mx);
            s += e; sl += e * lg[a2];
        }
        float logZ = mx + __logf(s);
        int act = action[row];
        float la = 0.f;
        #pragma unroll
        for (int a2 = 0; a2 < 18; a2++)
            if (a2 == act) la = lg[a2];
        out[row] = la - logZ;                          // log_prob
        out[32768 + row] = logZ - sl / s;              // entropy
        out[65536 + row] = cls[wave][lane][18] + b_critic[0];  // value
    }
}

// ---------------- launch ----------------
extern "C" void kernel_launch(void* const* d_in, const int* in_sizes, int n_in,
                              void* d_out, int out_size, void* d_ws, size_t ws_size,
                              hipStream_t stream) {
    const float* x        = (const float*)d_in[0];
    const float* gru_st   = (const float*)d_in[1];
    const float* done     = (const float*)d_in[2];
    const int*   action   = (const int*)d_in[3];
    const float* w1       = (const float*)d_in[4];
    const float* b1       = (const float*)d_in[5];
    const float* w2       = (const float*)d_in[6];
    const float* b2       = (const float*)d_in[7];
    const float* w_ih     = (const float*)d_in[8];
    const float* w_hh     = (const float*)d_in[9];
    const float* b_ih     = (const float*)d_in[10];
    const float* b_hh     = (const float*)d_in[11];
    const float* w_actor  = (const float*)d_in[12];
    const float* b_actor  = (const float*)d_in[13];
    const float* w_critic = (const float*)d_in[14];
    const float* b_critic = (const float*)d_in[15];
    float* out = (float*)d_out;

    // workspace layout (total 138,412,032 B ~= 132 MiB)
    char* ws = (char*)d_ws;
    u16* h1     = (u16*)(ws + 0LL);          // 16 MB   (dead after gemm2)
    u16* h2     = (u16*)(ws + 16777216LL);   // 16 MB   (dead after gemm3)
    u16* hidden = (u16*)(ws + 0LL);          // 33.5 MB (aliases h1+h2, written by scan)
    u16* w1b    = (u16*)(ws + 33554432LL);
    u16* w2b    = (u16*)(ws + 33816576LL);
    u16* wihb   = (u16*)(ws + 33947648LL);
    u16* wcatb  = (u16*)(ws + 34734080LL);
    u16* h_pub  = (u16*)(ws + 34766848LL);   // 0.5 MB
    int* flags  = (int*)(ws + 35291136LL);   // 8.2 KB
    u16* gxb    = (u16*)(ws + 37748736LL);   // 100.7 MB -> ends at 138,412,032
    float* h_last = out + 3 * 32768;

    hipMemsetAsync(flags, 0, 129 * 16 * 4, stream);
    prep_kernel<<<592, 256, 0, stream>>>(w1, w2, w_ih, w_actor, w_critic,
                                         w1b, w2b, wihb, wcatb);
    gemm_a32_bt_kernel<<<512, 256, 0, stream>>>(x, w1b, b1, h1, 32768, 256, 512);
    gemm_bt_kernel<<<512, 256, 0, stream>>>(h1, w2b, b2, h2, 32768, 256, 256, 0);
    gemm_bt_kernel<<<3072, 256, 0, stream>>>(h2, wihb, b_ih, gxb, 32768, 1536, 256, 1);

    void* args[] = {(void*)&gru_st, (void*)&done, (void*)&w_hh, (void*)&b_hh,
                    (void*)&gxb, (void*)&h_pub, (void*)&hidden, (void*)&h_last,
                    (void*)&flags};
    hipLaunchCooperativeKernel((void*)scan_kernel, dim3(256), dim3(256), args, 0, stream);

    heads_kernel<<<512, 256, 0, stream>>>(hidden, wcatb, b_actor, b_critic, action, out);
}

// Round 3
// 667.297 us; speedup vs baseline: 2.6060x; 2.6060x over previous
//
#include <hip/hip_runtime.h>
#include <hip/hip_bf16.h>

typedef short bf16x8 __attribute__((ext_vector_type(8)));
typedef float f32x4 __attribute__((ext_vector_type(4)));
typedef unsigned short u16;
typedef unsigned int u32;
typedef unsigned long long u64;

#define AS1 __attribute__((address_space(1)))
#define AS3 __attribute__((address_space(3)))

__device__ __forceinline__ u16 f2bf(float f) {
    __hip_bfloat16 h = __float2bfloat16(f);
    u16 r;
    __builtin_memcpy(&r, &h, 2);
    return r;
}
__device__ __forceinline__ float bf2f(u16 u) {
    u32 v = ((u32)u) << 16;
    float f;
    __builtin_memcpy(&f, &v, 4);
    return f;
}

// T=128 B=256 OBS=512 ENC=256 H=512 A=18 N=32768

// ---------------- prep: weight fp32 -> bf16 conversions (x handled in gemm1) ----------------
constexpr int NW1  = 256 * 512;
constexpr int NW2  = 256 * 256;
constexpr int NWIH = 1536 * 256;

__global__ __launch_bounds__(256) void prep_kernel(
    const float* __restrict__ w1, const float* __restrict__ w2,
    const float* __restrict__ wih, const float* __restrict__ wact,
    const float* __restrict__ wcrit,
    u16* __restrict__ w1b, u16* __restrict__ w2b,
    u16* __restrict__ wihb, u16* __restrict__ wcatb) {
    long long gid = (long long)blockIdx.x * 256 + threadIdx.x;
    long long i4 = gid * 4;
    const float* src;
    u16* dst;
    if (i4 < NW1) { src = w1; dst = w1b; }
    else if ((i4 -= NW1) < NW2) { src = w2; dst = w2b; }
    else if ((i4 -= NW2) < NWIH) { src = wih; dst = wihb; }
    else {
        i4 -= NWIH;  // wcat region, 32x512 padded actor(18)+critic(1)+zeros
        #pragma unroll
        for (int e = 0; e < 4; e++) {
            long long idx = i4 + e;
            int row = (int)(idx >> 9), col = (int)(idx & 511);
            float v = (row < 18) ? wact[row * 512 + col]
                    : (row == 18 ? wcrit[col] : 0.f);
            wcatb[idx] = f2bf(v);
        }
        return;
    }
    float4 v = *reinterpret_cast<const float4*>(src + i4);
    uint2 p;
    p.x = (u32)f2bf(v.x) | ((u32)f2bf(v.y) << 16);
    p.y = (u32)f2bf(v.z) | ((u32)f2bf(v.w) << 16);
    *reinterpret_cast<uint2*>(dst + i4) = p;
}

// ---------------- GEMM1: C = relu(A_fp32 @ B^T + bias) -> bf16 ----------------
__global__ __launch_bounds__(256) void gemm_a32_bt_kernel(
    const float* __restrict__ A, const u16* __restrict__ B,
    const float* __restrict__ bias, u16* __restrict__ out,
    int M, int N, int K) {
    __shared__ u16 As[128 * 64];
    __shared__ u16 Bs[128 * 64];
    int tid = threadIdx.x;
    int lane = tid & 63, wave = tid >> 6;
    int m16 = lane & 15, quad = lane >> 4;
    int nb = N >> 7;
    int bm = blockIdx.x / nb, bn = blockIdx.x % nb;
    int wm = wave >> 1, wn = wave & 1;

    f32x4 acc[4][4];
    #pragma unroll
    for (int i = 0; i < 4; i++)
        #pragma unroll
        for (int j = 0; j < 4; j++) acc[i][j] = (f32x4){0.f, 0.f, 0.f, 0.f};

    const int rbase = wave * 32 + (lane >> 3);
    const int cpr = lane & 7;
    const int ar = tid >> 1, ah = (tid & 1) * 32;  // A-staging: 2 threads/row
    int kiters = K >> 6;
    for (int kb = 0; kb < kiters; kb++) {
        #pragma unroll
        for (int i = 0; i < 4; i++) {
            int r = rbase + i * 8;
            int cg = cpr ^ (r & 7);
            const u16* gb_ = B + (long long)(bn * 128 + r) * K + kb * 64 + cg * 8;
            __builtin_amdgcn_global_load_lds((const AS1 u32*)gb_, (AS3 u32*)&Bs[r * 64 + cpr * 8], 16, 0, 0);
        }
        const float* ga = A + (long long)(bm * 128 + ar) * K + kb * 64 + ah;
        #pragma unroll
        for (int g = 0; g < 4; g++) {
            float4 v0 = *reinterpret_cast<const float4*>(ga + g * 8);
            float4 v1 = *reinterpret_cast<const float4*>(ga + g * 8 + 4);
            uint4 pk;
            pk.x = (u32)f2bf(v0.x) | ((u32)f2bf(v0.y) << 16);
            pk.y = (u32)f2bf(v0.z) | ((u32)f2bf(v0.w) << 16);
            pk.z = (u32)f2bf(v1.x) | ((u32)f2bf(v1.y) << 16);
            pk.w = (u32)f2bf(v1.z) | ((u32)f2bf(v1.w) << 16);
            int sc = ((ah >> 3) + g) ^ (ar & 7);  // XOR swizzle
            *reinterpret_cast<uint4*>(&As[ar * 64 + sc * 8]) = pk;
        }
        __syncthreads();
        #pragma unroll
        for (int ks = 0; ks < 2; ks++) {
            bf16x8 af[4], bfr[4];
            int lc = ks * 4 + quad;
            #pragma unroll
            for (int mt = 0; mt < 4; mt++) {
                int m = wm * 64 + mt * 16 + m16;
                af[mt] = *reinterpret_cast<const bf16x8*>(&As[m * 64 + (lc ^ (m & 7)) * 8]);
            }
            #pragma unroll
            for (int nt = 0; nt < 4; nt++) {
                int n = wn * 64 + nt * 16 + m16;
                bfr[nt] = *reinterpret_cast<const bf16x8*>(&Bs[n * 64 + (lc ^ (n & 7)) * 8]);
            }
            #pragma unroll
            for (int mt = 0; mt < 4; mt++)
                #pragma unroll
                for (int nt = 0; nt < 4; nt++)
                    acc[mt][nt] = __builtin_amdgcn_mfma_f32_16x16x32_bf16(af[mt], bfr[nt], acc[mt][nt], 0, 0, 0);
        }
        __syncthreads();
    }
    #pragma unroll
    for (int nt = 0; nt < 4; nt++) {
        int n = bn * 128 + wn * 64 + nt * 16 + m16;
        float bv = bias[n];
        #pragma unroll
        for (int mt = 0; mt < 4; mt++) {
            #pragma unroll
            for (int i = 0; i < 4; i++) {
                int m = bm * 128 + wm * 64 + mt * 16 + quad * 4 + i;
                float v = acc[mt][nt][i] + bv;
                out[(long long)m * N + n] = f2bf(fmaxf(v, 0.f));
            }
        }
    }
}

// ---------------- tiled GEMM: bf16 A/B. mode 0: relu->bf16 rowmajor. mode 1: gx scatter bf16 ----------------
__global__ __launch_bounds__(256) void gemm_bt_kernel(
    const u16* __restrict__ A, const u16* __restrict__ B,
    const float* __restrict__ bias, u16* __restrict__ out,
    int M, int N, int K, int mode) {
    __shared__ u16 As[128 * 64];
    __shared__ u16 Bs[128 * 64];
    int tid = threadIdx.x;
    int lane = tid & 63, wave = tid >> 6;
    int m16 = lane & 15, quad = lane >> 4;
    int nb = N >> 7;
    int bm = blockIdx.x / nb, bn = blockIdx.x % nb;
    int wm = wave >> 1, wn = wave & 1;

    f32x4 acc[4][4];
    #pragma unroll
    for (int i = 0; i < 4; i++)
        #pragma unroll
        for (int j = 0; j < 4; j++) acc[i][j] = (f32x4){0.f, 0.f, 0.f, 0.f};

    const int rbase = wave * 32 + (lane >> 3);
    const int cpr = lane & 7;
    int kiters = K >> 6;
    for (int kb = 0; kb < kiters; kb++) {
        #pragma unroll
        for (int i = 0; i < 4; i++) {
            int r = rbase + i * 8;
            int cg = cpr ^ (r & 7);
            const u16* ga = A + (long long)(bm * 128 + r) * K + kb * 64 + cg * 8;
            const u16* gb_ = B + (long long)(bn * 128 + r) * K + kb * 64 + cg * 8;
            __builtin_amdgcn_global_load_lds((const AS1 u32*)ga, (AS3 u32*)&As[r * 64 + cpr * 8], 16, 0, 0);
            __builtin_amdgcn_global_load_lds((const AS1 u32*)gb_, (AS3 u32*)&Bs[r * 64 + cpr * 8], 16, 0, 0);
        }
        __syncthreads();
        #pragma unroll
        for (int ks = 0; ks < 2; ks++) {
            bf16x8 af[4], bfr[4];
            int lc = ks * 4 + quad;
            #pragma unroll
            for (int mt = 0; mt < 4; mt++) {
                int m = wm * 64 + mt * 16 + m16;
                af[mt] = *reinterpret_cast<const bf16x8*>(&As[m * 64 + (lc ^ (m & 7)) * 8]);
            }
            #pragma unroll
            for (int nt = 0; nt < 4; nt++) {
                int n = wn * 64 + nt * 16 + m16;
                bfr[nt] = *reinterpret_cast<const bf16x8*>(&Bs[n * 64 + (lc ^ (n & 7)) * 8]);
            }
            #pragma unroll
            for (int mt = 0; mt < 4; mt++)
                #pragma unroll
                for (int nt = 0; nt < 4; nt++)
                    acc[mt][nt] = __builtin_amdgcn_mfma_f32_16x16x32_bf16(af[mt], bfr[nt], acc[mt][nt], 0, 0, 0);
        }
        __syncthreads();
    }
    if (mode == 0) {
        #pragma unroll
        for (int nt = 0; nt < 4; nt++) {
            int n = bn * 128 + wn * 64 + nt * 16 + m16;
            float bv = bias[n];
            #pragma unroll
            for (int mt = 0; mt < 4; mt++) {
                #pragma unroll
                for (int i = 0; i < 4; i++) {
                    int m = bm * 128 + wm * 64 + mt * 16 + quad * 4 + i;
                    float v = acc[mt][nt][i] + bv;
                    out[(long long)m * N + n] = f2bf(fmaxf(v, 0.f));
                }
            }
        }
    } else {
        // gx scatter (bf16): [t][gb][gu][b_local(16)][gate_local(96)]
        #pragma unroll
        for (int nt = 0; nt < 4; nt++) {
            int n = bn * 128 + wn * 64 + nt * 16 + m16;
            float bv = bias[n];
            int gkind = n >> 9, gj = n & 511;
            int gu = gj >> 5;
            int gate_local = gkind * 32 + (gj & 31);
            #pragma unroll
            for (int mt = 0; mt < 4; mt++) {
                #pragma unroll
                for (int i = 0; i < 4; i++) {
                    int m = bm * 128 + wm * 64 + mt * 16 + quad * 4 + i;
                    int t = m >> 8, bg = m & 255;
                    long long dst = ((((long long)t * 16 + (bg >> 4)) * 16 + gu) * 16 + (bg & 15)) * 96 + gate_local;
                    out[dst] = f2bf(acc[mt][nt][i] + bv);
                }
            }
        }
    }
}

// ---------------- GRU scan (cooperative, 256 wgs = 16 batch-groups x 16 unit-groups) ----------------
// Sync protocol: sc1 (device-coherent) data stores -> __syncthreads (per-wave vmcnt
// drain) -> ONE relaxed sc1 flag store per wg, step-stamped (flags[gb][gu] = t+2 means
// h(t+1) published). Consumers: 16 lanes poll 16 producer flags in parallel (relaxed
// sc1 loads), then __syncthreads, then sc1 data loads. No RMW, no acquire/release
// cache maintenance (no buffer_wbl2 / buffer_inv) anywhere in the loop.
__global__ __launch_bounds__(256) void scan_kernel(
    const float* __restrict__ gru_state, const float* __restrict__ done,
    const float* __restrict__ w_hh, const float* __restrict__ b_hh,
    const u16* __restrict__ gx, u16* h_pub, u16* hidden,
    float* h_last, int* flags) {
    __shared__ u16 h_lds[16 * 520];          // 16 batch rows x 512 (+8 pad)
    __shared__ float partial[4][16][104];    // K-split partials, stride 104 (bank-conflict-free)
    int tid = threadIdx.x;
    int lane = tid & 63, wave = tid >> 6;
    int m16 = lane & 15, quad = lane >> 4;
    int gb = blockIdx.x & 15, gu = blockIdx.x >> 4;

    // w_hh slice -> register-resident MFMA B-fragments (fp32->bf16, loaded once)
    bf16x8 wfrag[6][4];
    #pragma unroll
    for (int nt = 0; nt < 6; nt++) {
        int g = nt * 16 + m16;                       // local gate 0..95
        int row = (g >> 5) * 512 + gu * 32 + (g & 31);
        #pragma unroll
        for (int ks = 0; ks < 4; ks++) {
            int k0 = wave * 128 + ks * 32 + quad * 8;
            const float* wp = w_hh + row * 512 + k0;
            float4 v0 = *reinterpret_cast<const float4*>(wp);
            float4 v1 = *reinterpret_cast<const float4*>(wp + 4);
            bf16x8 f;
            f[0] = (short)f2bf(v0.x); f[1] = (short)f2bf(v0.y);
            f[2] = (short)f2bf(v0.z); f[3] = (short)f2bf(v0.w);
            f[4] = (short)f2bf(v1.x); f[5] = (short)f2bf(v1.y);
            f[6] = (short)f2bf(v1.z); f[7] = (short)f2bf(v1.w);
            wfrag[nt][ks] = f;
        }
    }
    int b_ = tid >> 4, jj = (tid & 15) * 2;   // owned element pair (b_, jj/jj+1)
    int bglob = gb * 16 + b_;
    int unit = gu * 32 + jj;
    float bhr0 = b_hh[unit],        bhr1 = b_hh[unit + 1];
    float bhz0 = b_hh[512 + unit],  bhz1 = b_hh[512 + unit + 1];
    float bhn0 = b_hh[1024 + unit], bhn1 = b_hh[1024 + unit + 1];
    float hs0 = gru_state[bglob * 512 + unit];
    float hs1 = gru_state[bglob * 512 + unit + 1];

    // publish h(0) into buffer 0
    {
        u32 p = (u32)f2bf(hs0) | ((u32)f2bf(hs1) << 16);
        u32* dst = (u32*)h_pub + (bglob * 512 + unit) / 2;
        __hip_atomic_store(dst, p, __ATOMIC_RELAXED, __HIP_MEMORY_SCOPE_AGENT);
    }
    __syncthreads();   // drains each wave's vmcnt before barrier -> data in L3
    if (tid == 0)
        __hip_atomic_store(&flags[gb * 16 + gu], 1, __ATOMIC_RELAXED, __HIP_MEMORY_SCOPE_AGENT);

    const int fillcol = (tid & 15) * 32;
    for (int t = 0; t < 128; t++) {
        // prefetch gx / done (issued before the flag wait; latency hidden)
        const u16* gxp = gx + ((size_t)((t * 16 + gb) * 16 + gu) * 16 + b_) * 96;
        u32 pr = *reinterpret_cast<const u32*>(gxp + jj);
        u32 pz = *reinterpret_cast<const u32*>(gxp + 32 + jj);
        u32 pn = *reinterpret_cast<const u32*>(gxp + 64 + jj);
        float grx = bf2f((u16)pr), gry = bf2f((u16)(pr >> 16));
        float gzx = bf2f((u16)pz), gzy = bf2f((u16)(pz >> 16));
        float gnx = bf2f((u16)pn), gny = bf2f((u16)(pn >> 16));
        float dne = done[t * 256 + bglob];

        // wait until all 16 producers of batch-group gb have published h(t)
        if (tid < 16) {
            while (__hip_atomic_load(&flags[gb * 16 + tid], __ATOMIC_RELAXED, __HIP_MEMORY_SCOPE_AGENT) < t + 1) {}
        }
        __syncthreads();
        // fill h_lds row b_ cols [fillcol, fillcol+32) from h_pub[t&1], applying done reset
        {
            const u64* src = (const u64*)(h_pub + (size_t)(t & 1) * (256 * 512)) + (bglob * 512 + fillcol) / 4;
            bool keep = dne < 0.5f;   // done is exactly 0.0/1.0
            #pragma unroll
            for (int q = 0; q < 8; q++) {
                u64 v = __hip_atomic_load((u64*)(src + q), __ATOMIC_RELAXED, __HIP_MEMORY_SCOPE_AGENT);
                if (!keep) v = 0;
                *reinterpret_cast<u64*>(&h_lds[b_ * 520 + fillcol + q * 4]) = v;
            }
        }
        __syncthreads();
        // gh slice = h(16x512) @ w_hh_slice^T(96x512): K-split over 4 waves
        f32x4 acc[6];
        #pragma unroll
        for (int nt = 0; nt < 6; nt++) acc[nt] = (f32x4){0.f, 0.f, 0.f, 0.f};
        #pragma unroll
        for (int ks = 0; ks < 4; ks++) {
            bf16x8 a = *reinterpret_cast<const bf16x8*>(&h_lds[m16 * 520 + wave * 128 + ks * 32 + quad * 8]);
            #pragma unroll
            for (int nt = 0; nt < 6; nt++)
                acc[nt] = __builtin_amdgcn_mfma_f32_16x16x32_bf16(a, wfrag[nt][ks], acc[nt], 0, 0, 0);
        }
        #pragma unroll
        for (int nt = 0; nt < 6; nt++)
            #pragma unroll
            for (int i = 0; i < 4; i++)
                partial[wave][quad * 4 + i][nt * 16 + m16] = acc[nt][i];
        __syncthreads();
        // reduce K-split partials + gates (each thread: 2 hidden units)
        float sr0 = 0, sr1 = 0, sz0 = 0, sz1 = 0, sn0 = 0, sn1 = 0;
        #pragma unroll
        for (int w = 0; w < 4; w++) {
            const float* p = &partial[w][b_][0];
            float2 a0 = *reinterpret_cast<const float2*>(p + jj);
            float2 a1 = *reinterpret_cast<const float2*>(p + 32 + jj);
            float2 a2 = *reinterpret_cast<const float2*>(p + 64 + jj);
            sr0 += a0.x; sr1 += a0.y;
            sz0 += a1.x; sz1 += a1.y;
            sn0 += a2.x; sn1 += a2.y;
        }
        float scale = 1.f - dne;
        hs0 *= scale; hs1 *= scale;
        float r0 = 1.f / (1.f + __expf(-(grx + sr0 + bhr0)));
        float r1 = 1.f / (1.f + __expf(-(gry + sr1 + bhr1)));
        float z0 = 1.f / (1.f + __expf(-(gzx + sz0 + bhz0)));
        float z1 = 1.f / (1.f + __expf(-(gzy + sz1 + bhz1)));
        float pn0 = gnx + r0 * (sn0 + bhn0);
        float pn1 = gny + r1 * (sn1 + bhn1);
        float n0 = 1.f - 2.f / (__expf(2.f * pn0) + 1.f);   // tanh
        float n1 = 1.f - 2.f / (__expf(2.f * pn1) + 1.f);
        hs0 = (1.f - z0) * n0 + z0 * hs0;
        hs1 = (1.f - z1) * n1 + z1 * hs1;
        u32 packed = (u32)f2bf(hs0) | ((u32)f2bf(hs1) << 16);
        ((u32*)hidden)[((long long)(t * 256 + bglob) * 512 + unit) / 2] = packed;
        if (t < 127) {
            u32* dst = (u32*)(h_pub + (size_t)((t + 1) & 1) * (256 * 512)) + (bglob * 512 + unit) / 2;
            __hip_atomic_store(dst, packed, __ATOMIC_RELAXED, __HIP_MEMORY_SCOPE_AGENT);
        } else {
            h_last[bglob * 512 + unit] = hs0;
            h_last[bglob * 512 + unit + 1] = hs1;
        }
        __syncthreads();   // per-wave vmcnt drain: publish stores are in L3 past here
        if (tid == 0 && t < 127)
            __hip_atomic_store(&flags[gb * 16 + gu], t + 2, __ATOMIC_RELAXED, __HIP_MEMORY_SCOPE_AGENT);
    }
}

// ---------------- heads: logits/log_softmax/entropy/value ----------------
__global__ __launch_bounds__(256) void heads_kernel(
    const u16* __restrict__ hidden, const u16* __restrict__ wcat,
    const float* __restrict__ b_actor, const float* __restrict__ b_critic,
    const int* __restrict__ action, float* __restrict__ out) {
    __shared__ float cls[4][16][34];
    int tid = threadIdx.x, lane = tid & 63, wave = tid >> 6;
    int m16 = lane & 15, quad = lane >> 4;
    int r0 = (blockIdx.x * 4 + wave) * 16;
    f32x4 acc0 = (f32x4){0.f, 0.f, 0.f, 0.f}, acc1 = (f32x4){0.f, 0.f, 0.f, 0.f};
    #pragma unroll
    for (int ks = 0; ks < 16; ks++) {
        bf16x8 a = *reinterpret_cast<const bf16x8*>(&hidden[(long long)(r0 + m16) * 512 + ks * 32 + quad * 8]);
        bf16x8 b0 = *reinterpret_cast<const bf16x8*>(&wcat[m16 * 512 + ks * 32 + quad * 8]);
        bf16x8 b1 = *reinterpret_cast<const bf16x8*>(&wcat[(16 + m16) * 512 + ks * 32 + quad * 8]);
        acc0 = __builtin_amdgcn_mfma_f32_16x16x32_bf16(a, b0, acc0, 0, 0, 0);
        acc1 = __builtin_amdgcn_mfma_f32_16x16x32_bf16(a, b1, acc1, 0, 0, 0);
    }
    #pragma unroll
    for (int i = 0; i < 4; i++) {
        cls[wave][quad * 4 + i][m16] = acc0[i];
        cls[wave][quad * 4 + i][16 + m16] = acc1[i];
    }
    __syncthreads();
    if (lane < 16) {
        int row = r0 + lane;
        float lg[18];
        float mx = -1e30f;
        #pragma unroll
        for (int a2 = 0; a2 < 18; a2++) {
            lg[a2] = cls[wave][lane][a2] + b_actor[a2];
            mx = fmaxf(mx, lg[a2]);
        }
        float s = 0.f, sl = 0.f;
        #pragma unroll
        for (int a2 = 0; a2 < 18; a2++) {
            float e = __expf(lg[a2] - mx);
            s += e; sl += e * lg[a2];
        }
        float logZ = mx + __logf(s);
        int act = action[row];
        float la = 0.f;
        #pragma unroll
        for (int a2 = 0; a2 < 18; a2++)
            if (a2 == act) la = lg[a2];
        out[row] = la - logZ;                          // log_prob
        out[32768 + row] = logZ - sl / s;              // entropy
        out[65536 + row] = cls[wave][lane][18] + b_critic[0];  // value
    }
}

// ---------------- launch ----------------
extern "C" void kernel_launch(void* const* d_in, const int* in_sizes, int n_in,
                              void* d_out, int out_size, void* d_ws, size_t ws_size,
                              hipStream_t stream) {
    const float* x        = (const float*)d_in[0];
    const float* gru_st   = (const float*)d_in[1];
    const float* done     = (const float*)d_in[2];
    const int*   action   = (const int*)d_in[3];
    const float* w1       = (const float*)d_in[4];
    const float* b1       = (const float*)d_in[5];
    const float* w2       = (const float*)d_in[6];
    const float* b2       = (const float*)d_in[7];
    const float* w_ih     = (const float*)d_in[8];
    const float* w_hh     = (const float*)d_in[9];
    const float* b_ih     = (const float*)d_in[10];
    const float* b_hh     = (const float*)d_in[11];
    const float* w_actor  = (const float*)d_in[12];
    const float* b_actor  = (const float*)d_in[13];
    const float* w_critic = (const float*)d_in[14];
    const float* b_critic = (const float*)d_in[15];
    float* out = (float*)d_out;

    // workspace layout (total 138,412,032 B ~= 132 MiB)
    char* ws = (char*)d_ws;
    u16* h1     = (u16*)(ws + 0LL);          // 16 MB   (dead after gemm2)
    u16* h2     = (u16*)(ws + 16777216LL);   // 16 MB   (dead after gemm3)
    u16* hidden = (u16*)(ws + 0LL);          // 33.5 MB (aliases h1+h2, written by scan)
    u16* w1b    = (u16*)(ws + 33554432LL);
    u16* w2b    = (u16*)(ws + 33816576LL);
    u16* wihb   = (u16*)(ws + 33947648LL);
    u16* wcatb  = (u16*)(ws + 34734080LL);
    u16* h_pub  = (u16*)(ws + 34766848LL);   // 0.5 MB double buffer
    int* flags  = (int*)(ws + 35291136LL);   // 1 KB: flags[gb][gu] = steps published
    u16* gxb    = (u16*)(ws + 37748736LL);   // 100.7 MB
    float* h_last = out + 3 * 32768;

    hipMemsetAsync(flags, 0, 16 * 16 * 4, stream);
    prep_kernel<<<592, 256, 0, stream>>>(w1, w2, w_ih, w_actor, w_critic,
                                         w1b, w2b, wihb, wcatb);
    gemm_a32_bt_kernel<<<512, 256, 0, stream>>>(x, w1b, b1, h1, 32768, 256, 512);
    gemm_bt_kernel<<<512, 256, 0, stream>>>(h1, w2b, b2, h2, 32768, 256, 256, 0);
    gemm_bt_kernel<<<3072, 256, 0, stream>>>(h2, wihb, b_ih, gxb, 32768, 1536, 256, 1);

    void* args[] = {(void*)&gru_st, (void*)&done, (void*)&w_hh, (void*)&b_hh,
                    (void*)&gxb, (void*)&h_pub, (void*)&hidden, (void*)&h_last,
                    (void*)&flags};
    hipLaunchCooperativeKernel((void*)scan_kernel, dim3(256), dim3(256), args, 0, stream);

    heads_kernel<<<512, 256, 0, stream>>>(hidden, wcatb, b_actor, b_critic, action, out);
}